// Round 9
// baseline (751.219 us; speedup 1.0000x reference)
//
#include <hip/hip_runtime.h>
#include <hip/hip_bf16.h>
#include <stdint.h>

// Problem constants (B=2, L=2048 -> T=4096 tokens)
#define T_TOK 4096
#define DDIM  1024
#define IDIM  4096
#define NEXP  8
// padded row count for gathered matrices (worst-case 256-tile overhang)
#define GROWS (T_TOK*2 + 256)

typedef __attribute__((ext_vector_type(8))) short bfrag;   // 8 bf16 (4 VGPR)
typedef __attribute__((ext_vector_type(4))) float f32x4;   // MFMA accum

__device__ __forceinline__ unsigned short f2bf(float x) {
    unsigned int u = __float_as_uint(x);
    unsigned int r = u + 0x7FFFu + ((u >> 16) & 1u);   // RNE
    return (unsigned short)(r >> 16);
}
__device__ __forceinline__ float bf2f(unsigned short h) {
    return __uint_as_float(((unsigned int)h) << 16);
}

// async global->LDS, 16B per lane; LDS base must be wave-uniform
#define GLOAD16(gsrc, ldst)                                                     \
    __builtin_amdgcn_global_load_lds(                                           \
        (const __attribute__((address_space(1))) unsigned int*)(gsrc),          \
        (__attribute__((address_space(3))) unsigned int*)(ldst), 16, 0, 0)

// ---------------------------------------------------------------------------
// K1: per-token layernorm stats + xhat (bf16), fp32 router logits, top-2,
//     softmax -> per-slot weights; builds per-expert token lists via atomics.
// ---------------------------------------------------------------------------
__global__ __launch_bounds__(256) void router_kernel(
    const float* __restrict__ x,
    const float* __restrict__ rng, const float* __restrict__ rnb,
    const float* __restrict__ rw,  const float* __restrict__ rb,
    unsigned short* __restrict__ xhat,
    int* __restrict__ counts, int* __restrict__ tok_slot,
    float* __restrict__ wslot)
{
    const int t = blockIdx.x;
    const int tid = threadIdx.x;
    const int lane = tid & 63, wid = tid >> 6;

    float4 v = *(const float4*)(x + (size_t)t * DDIM + tid * 4);
    float s1 = v.x + v.y + v.z + v.w;
    float s2 = v.x*v.x + v.y*v.y + v.z*v.z + v.w*v.w;
    #pragma unroll
    for (int m = 32; m; m >>= 1) { s1 += __shfl_xor(s1, m, 64); s2 += __shfl_xor(s2, m, 64); }

    __shared__ float red[8];
    __shared__ float pl[4][8];
    __shared__ float bcast[2];
    if (lane == 0) { red[wid] = s1; red[wid + 4] = s2; }
    __syncthreads();
    if (tid == 0) {
        float S1 = red[0] + red[1] + red[2] + red[3];
        float S2 = red[4] + red[5] + red[6] + red[7];
        float mean = S1 * (1.f / 1024.f);
        float var  = S2 * (1.f / 1024.f) - mean * mean;
        bcast[0] = mean; bcast[1] = rsqrtf(var + 1e-5f);
    }
    __syncthreads();
    const float mean = bcast[0], rinv = bcast[1];

    float4 xh = { (v.x - mean) * rinv, (v.y - mean) * rinv,
                  (v.z - mean) * rinv, (v.w - mean) * rinv };
    ushort4 hx = { f2bf(xh.x), f2bf(xh.y), f2bf(xh.z), f2bf(xh.w) };
    *(ushort4*)(xhat + (size_t)t * DDIM + tid * 4) = hx;

    // router layernorm affine + logits (kept fp32 to match reference top-k)
    float4 g = *(const float4*)(rng + tid * 4);
    float4 b = *(const float4*)(rnb + tid * 4);
    float4 nm = { xh.x*g.x + b.x, xh.y*g.y + b.y, xh.z*g.z + b.z, xh.w*g.w + b.w };
    float p[8];
    #pragma unroll
    for (int e = 0; e < 8; e++) {
        float4 w = *(const float4*)(rw + e * DDIM + tid * 4);
        p[e] = nm.x*w.x + nm.y*w.y + nm.z*w.z + nm.w*w.w;
    }
    #pragma unroll
    for (int m = 32; m; m >>= 1) {
        #pragma unroll
        for (int e = 0; e < 8; e++) p[e] += __shfl_xor(p[e], m, 64);
    }
    if (lane == 0) {
        #pragma unroll
        for (int e = 0; e < 8; e++) pl[wid][e] = p[e];
    }
    __syncthreads();
    if (tid == 0) {
        float l[8];
        #pragma unroll
        for (int e = 0; e < 8; e++) l[e] = pl[0][e] + pl[1][e] + pl[2][e] + pl[3][e] + rb[e];
        int e0 = 0; float v0 = l[0];
        for (int e = 1; e < 8; e++) if (l[e] > v0) { v0 = l[e]; e0 = e; }
        int e1 = (e0 == 0) ? 1 : 0; float v1 = l[e1];
        for (int e = 0; e < 8; e++) if (e != e0 && l[e] > v1) { v1 = l[e]; e1 = e; }
        float ex = expf(v1 - v0);
        float w0 = 1.f / (1.f + ex);
        float w1 = ex * w0;
        int p0 = atomicAdd(&counts[e0], 1);
        tok_slot[e0 * T_TOK + p0] = (t << 1);
        int p1 = atomicAdd(&counts[e1], 1);
        tok_slot[e1 * T_TOK + p1] = (t << 1) | 1;
        wslot[t * 2]     = w0;
        wslot[t * 2 + 1] = w1;
    }
}

// K2: tiny exclusive prefix over 8 expert counts
__global__ void prefix_kernel(const int* __restrict__ counts, int* __restrict__ offs)
{
    if (threadIdx.x == 0) {
        int a = 0;
        for (int e = 0; e < 8; e++) { offs[e] = a; a += counts[e]; }
    }
}

// ---------------------------------------------------------------------------
// K3: build compacted per-expert A matrix: Agath[off[e]+pos][d] =
//     bf16( xhat[t][d]*ln_g[e][d] + ln_b[e][d] ), plus rowinfo for scatter.
// ---------------------------------------------------------------------------
__global__ __launch_bounds__(256) void gather_kernel(
    const unsigned short* __restrict__ xhat,
    const float* __restrict__ lng, const float* __restrict__ lnb,
    const int* __restrict__ counts, const int* __restrict__ offs,
    const int* __restrict__ tok_slot,
    unsigned short* __restrict__ Agath, int* __restrict__ rowinfo)
{
    const int e = blockIdx.y, pos = blockIdx.x;
    if (pos >= counts[e]) return;
    const int grow = offs[e] + pos;
    const int info = tok_slot[e * T_TOK + pos];
    if (threadIdx.x == 0) rowinfo[grow] = info;
    const int t = info >> 1;
    const int d = threadIdx.x * 4;
    ushort4 hx = *(const ushort4*)(xhat + (size_t)t * DDIM + d);
    float4 g = *(const float4*)(lng + (size_t)e * DDIM + d);
    float4 b = *(const float4*)(lnb + (size_t)e * DDIM + d);
    ushort4 o = { f2bf(bf2f(hx.x) * g.x + b.x),
                  f2bf(bf2f(hx.y) * g.y + b.y),
                  f2bf(bf2f(hx.z) * g.z + b.z),
                  f2bf(bf2f(hx.w) * g.w + b.w) };
    *(ushort4*)(Agath + (size_t)grow * DDIM + d) = o;
}

// ---------------------------------------------------------------------------
// K4: transpose+convert weights: W [E][Kd][Nd] fp32 -> WT [E][Nd][Kd] bf16.
// ---------------------------------------------------------------------------
__global__ __launch_bounds__(256) void transpose_kernel(
    const float* __restrict__ W, unsigned short* __restrict__ WT,
    int Kd, int Nd)
{
    const int e  = blockIdx.z;
    const int k0 = blockIdx.y * 64;
    const int n  = blockIdx.x * 256 + threadIdx.x;
    const float* src = W + (size_t)e * Kd * Nd + (size_t)k0 * Nd + n;
    unsigned short* dst = WT + ((size_t)e * Nd + n) * Kd + k0;
    unsigned short buf[64];
    #pragma unroll
    for (int j = 0; j < 64; j++)
        buf[j] = f2bf(src[(size_t)j * Nd]);
    #pragma unroll
    for (int c = 0; c < 8; c++)
        *(int4*)(dst + c * 8) = *(const int4*)(buf + c * 8);
}

// ---------------------------------------------------------------------------
// GEMM, deep-pipelined (T3+T4): BM=256 x BN=128 tile, BK=64, 8 waves (4Mx2N,
// per-wave 64x64, acc[4][4]). 3-slot LDS ring (48KB/slot = A 32KB + B 16KB),
// depth-2 prefetch with counted vmcnt(6) (never drained to 0 in-loop).
//
// LDS layout = CONSUME-ORDER fragments (conflict-free by construction):
//   A slot: [i_glob 0..15][kk 0..1][lane 0..63][16B]   (chunk c = i_glob*2+kk)
//   B slot: [j_glob 0..7 ][kk 0..1][lane 0..63][16B]
// Every ds_read_b128 is base + lane*16 (linear, 0 bank conflicts, immediate
// offsets); the permutation is carried by the per-lane GLOBAL source address
// of global_load_lds (both-sides-or-neither rule).
//
// Race safety: at tile top, each wave does lgkmcnt(0) (its slot-(t-1) reads
// complete) then vmcnt(6) (its stage(t) landed) then s_barrier -> after the
// barrier, slot t is fully resident and slot (t+2)%3==(t-1)%3 is free to be
// overwritten by the stage(t+2) issues inside tile t.
//
// Grid: 1-D, b -> e = b&7 (expert pinned to XCD), r=b>>3, mt=r&15 (inner),
// nt=r>>4. Concurrent blocks on an XCD share the B n-panel and stream A[e]
// (WS ~2.7MB < 4MB L2).
// EPI=0: +b1, exact GELU -> H (bf16). EPI=1: +b2, *combine-w, atomicAdd out.
// ---------------------------------------------------------------------------
template<int EPI>
__global__ __launch_bounds__(512, 2) void gemm_kernel(
    const unsigned short* __restrict__ Asrc,
    const unsigned short* __restrict__ Bsrc,
    const float* __restrict__ bias,
    const int* __restrict__ counts,
    const int* __restrict__ offs,
    const int* __restrict__ rowinfo,
    const float* __restrict__ wslot,
    unsigned short* __restrict__ Hout,
    float* __restrict__ Out,
    int Kd, int Nd)
{
    const int b  = blockIdx.x;
    const int e  = b & 7;
    const int r  = b >> 3;
    const int mt = r & 15;            // M-tile, inner (shares B panel on XCD)
    const int nt = r >> 4;            // N-tile
    const int ne = counts[e];
    if (mt * 256 >= ne) return;
    const int n0 = nt * 128;
    const int growbase = offs[e] + mt * 256;

    const int tid  = threadIdx.x;     // 0..511
    const int lane = tid & 63;
    const int wid  = tid >> 6;        // 0..7
    const int wm   = wid >> 1;        // 0..3 (M)
    const int wn   = wid & 1;         // 0..1 (N)

    // 3 slots x 48KB = 144KB
    __shared__ unsigned short S[3 * 24576];
    char* const Sb = (char*)S;

    f32x4 acc[4][4];
    #pragma unroll
    for (int i = 0; i < 4; i++)
        #pragma unroll
        for (int j = 0; j < 4; j++)
            acc[i][j] = (f32x4){0.f, 0.f, 0.f, 0.f};

    const unsigned short* Abase = Asrc + (size_t)growbase * Kd;
    const unsigned short* Bbase = Bsrc + ((size_t)e * Nd + n0) * Kd;
    // per-lane source offset inside a chunk: row (lane&15), k-sub (lane>>4)*8
    const int laneoff = (lane & 15) * Kd + (lane >> 4) * 8;

    // stage chunk c of tile q: A chunks c=wid+8m (m=0..3), B chunks c=wid+8m (m=0..1)
    #define STAGE_A(q, m) do {                                                    \
        const int c_ = wid + 8 * (m);                                             \
        GLOAD16(Abase + (size_t)((c_ >> 1) * 16) * Kd + laneoff                    \
                      + (q) * 64 + (c_ & 1) * 32,                                  \
                Sb + ((q) % 3) * 49152 + c_ * 1024);                               \
    } while (0)
    #define STAGE_B(q, m) do {                                                    \
        const int c_ = wid + 8 * (m);                                             \
        GLOAD16(Bbase + (size_t)((c_ >> 1) * 16) * Kd + laneoff                    \
                      + (q) * 64 + (c_ & 1) * 32,                                  \
                Sb + ((q) % 3) * 49152 + 32768 + c_ * 1024);                       \
    } while (0)

    const int ntile = Kd >> 6;        // >= 16

    // ---- prologue: stage tiles 0 and 1 (12 loads/wave in flight) ----
    STAGE_A(0, 0); STAGE_A(0, 1); STAGE_A(0, 2); STAGE_A(0, 3);
    STAGE_B(0, 0); STAGE_B(0, 1);
    STAGE_A(1, 0); STAGE_A(1, 1); STAGE_A(1, 2); STAGE_A(1, 3);
    STAGE_B(1, 0); STAGE_B(1, 1);

    for (int t = 0; t < ntile; ++t) {
        const char* Aslot = Sb + (t % 3) * 49152;
        const char* Bslot = Aslot + 32768;

        // tile-top sync: own LDS reads of t-1 done; own stage(t) landed; join.
        asm volatile("s_waitcnt lgkmcnt(0)" ::: "memory");
        if (t < ntile - 1) asm volatile("s_waitcnt vmcnt(6)" ::: "memory");
        else               asm volatile("s_waitcnt vmcnt(0)" ::: "memory");
        __builtin_amdgcn_s_barrier();

        const bool pf = (t + 2 < ntile);

        // ---- phase a (kk = 0): issue 3 prefetch loads, 8 ds_read, 16 MFMA --
        if (pf) { STAGE_A(t + 2, 0); STAGE_A(t + 2, 1); STAGE_A(t + 2, 2); }
        {
            bfrag av[4], bv[4];
            #pragma unroll
            for (int i = 0; i < 4; i++)
                av[i] = *(const bfrag*)(Aslot + ((wm * 4 + i) * 2 + 0) * 1024 + lane * 16);
            #pragma unroll
            for (int j = 0; j < 4; j++)
                bv[j] = *(const bfrag*)(Bslot + ((wn * 4 + j) * 2 + 0) * 1024 + lane * 16);
            __builtin_amdgcn_s_setprio(1);
            #pragma unroll
            for (int i = 0; i < 4; i++)
                #pragma unroll
                for (int j = 0; j < 4; j++)
                    acc[i][j] = __builtin_amdgcn_mfma_f32_16x16x32_bf16(av[i], bv[j], acc[i][j], 0, 0, 0);
            __builtin_amdgcn_s_setprio(0);
        }
        __builtin_amdgcn_s_barrier();

        // ---- phase b (kk = 1): issue 3 prefetch loads, 8 ds_read, 16 MFMA --
        if (pf) { STAGE_A(t + 2, 3); STAGE_B(t + 2, 0); STAGE_B(t + 2, 1); }
        {
            bfrag av[4], bv[4];
            #pragma unroll
            for (int i = 0; i < 4; i++)
                av[i] = *(const bfrag*)(Aslot + ((wm * 4 + i) * 2 + 1) * 1024 + lane * 16);
            #pragma unroll
            for (int j = 0; j < 4; j++)
                bv[j] = *(const bfrag*)(Bslot + ((wn * 4 + j) * 2 + 1) * 1024 + lane * 16);
            __builtin_amdgcn_s_setprio(1);
            #pragma unroll
            for (int i = 0; i < 4; i++)
                #pragma unroll
                for (int j = 0; j < 4; j++)
                    acc[i][j] = __builtin_amdgcn_mfma_f32_16x16x32_bf16(av[i], bv[j], acc[i][j], 0, 0, 0);
            __builtin_amdgcn_s_setprio(0);
        }
    }
    #undef STAGE_A
    #undef STAGE_B

    // ---- epilogue (C/D layout: col = lane&15, row = (lane>>4)*4 + reg) ----
    const float* bg = bias + (size_t)e * Nd;
    #pragma unroll
    for (int i = 0; i < 4; i++) {
        #pragma unroll
        for (int rr = 0; rr < 4; rr++) {
            int mrow = wm * 64 + i * 16 + ((lane >> 4) << 2) + rr;
            int pos = mt * 256 + mrow;
            if (pos >= ne) continue;
            if constexpr (EPI == 0) {
                size_t rowoff = (size_t)(growbase + mrow) * Nd;
                #pragma unroll
                for (int j = 0; j < 4; j++) {
                    int col = n0 + wn * 64 + j * 16 + (lane & 15);
                    float y = acc[i][j][rr] + bg[col];
                    float gl = 0.5f * y * (1.f + erff(y * 0.70710678118654752f));
                    Hout[rowoff + col] = f2bf(gl);
                }
            } else {
                int info = rowinfo[growbase + mrow];
                float wg = wslot[info];
                float* op = Out + (size_t)(info >> 1) * Nd;
                #pragma unroll
                for (int j = 0; j < 4; j++) {
                    int col = n0 + wn * 64 + j * 16 + (lane & 15);
                    float y = acc[i][j][rr] + bg[col];
                    atomicAdd(op + col, wg * y);   // exactly 2 adds/elem -> deterministic
                }
            }
        }
    }
}

// ---------------------------------------------------------------------------
extern "C" void kernel_launch(void* const* d_in, const int* in_sizes, int n_in,
                              void* d_out, int out_size, void* d_ws, size_t ws_size,
                              hipStream_t stream)
{
    (void)in_sizes; (void)n_in;
    const float* hidden   = (const float*)d_in[0];
    const float* rn_g     = (const float*)d_in[1];
    const float* rn_b     = (const float*)d_in[2];
    const float* router_w = (const float*)d_in[3];
    const float* router_b = (const float*)d_in[4];
    const float* ln_g     = (const float*)d_in[5];
    const float* ln_b     = (const float*)d_in[6];
    const float* w1       = (const float*)d_in[7];
    const float* b1       = (const float*)d_in[8];
    const float* w2       = (const float*)d_in[9];
    const float* b2       = (const float*)d_in[10];
    float* out = (float*)d_out;

    // workspace layout (bytes), total ~162.2 MB
    //   xhat    @ 0           :  8,388,608  (4096 x 1024 bf16)
    //   Agath   @ 8,388,608   : 17,301,504  (8448 x 1024 bf16)
    //   H       @ 25,690,112  : 69,206,016  (8448 x 4096 bf16)
    //   WT      @ 94,896,128  : 67,108,864  (W1T, then reused for W2T)
    //   counts  @ 162,004,992 / offs / tok_slot / rowinfo / wslot
    char* ws = (char*)d_ws;
    unsigned short* xhat   = (unsigned short*)ws;
    unsigned short* Agath  = (unsigned short*)(ws + 8388608);
    unsigned short* H      = (unsigned short*)(ws + 25690112);
    unsigned short* WT     = (unsigned short*)(ws + 94896128);
    int*   counts   = (int*)(ws + 162004992);
    int*   offs     = (int*)(ws + 162005024);
    int*   tok_slot = (int*)(ws + 162005056);
    int*   rowinfo  = (int*)(ws + 162136128);
    float* wslot    = (float*)(ws + 162169920);
    if (ws_size < 162202688) return;   // fail loudly (validation will catch it)

    hipMemsetAsync(counts, 0, 64, stream);                 // counts + offs
    hipMemsetAsync(d_out, 0, (size_t)out_size * sizeof(float), stream);

    // W1 [8][1024][4096] -> W1T [8][4096][1024]
    transpose_kernel<<<dim3(IDIM / 256, DDIM / 64, NEXP), 256, 0, stream>>>(w1, WT, DDIM, IDIM);
    router_kernel<<<T_TOK, 256, 0, stream>>>(hidden, rn_g, rn_b, router_w, router_b,
                                             xhat, counts, tok_slot, wslot);
    prefix_kernel<<<1, 64, 0, stream>>>(counts, offs);
    gather_kernel<<<dim3(T_TOK, NEXP), 256, 0, stream>>>(xhat, ln_g, ln_b, counts, offs,
                                                         tok_slot, Agath, rowinfo);
    // GEMM1: [rows x 1024] x [1024 x 4096] + b1, GELU -> H
    //   grid = 8 experts x 16 mt x (4096/128) nt, 1-D, expert = b&7 (XCD pin)
    gemm_kernel<0><<<dim3(8 * 16 * (IDIM / 128)), 512, 0, stream>>>(
        Agath, WT, b1, counts, offs, rowinfo, wslot, H, nullptr, DDIM, IDIM);
    // W2 [8][4096][1024] -> W2T [8][1024][4096] (reuses WT buffer after GEMM1)
    transpose_kernel<<<dim3(DDIM / 256, IDIM / 64, NEXP), 256, 0, stream>>>(w2, WT, IDIM, DDIM);
    // GEMM2: [rows x 4096] x [4096 x 1024] + b2, *w, scatter-add -> out
    gemm_kernel<1><<<dim3(8 * 16 * (DDIM / 128)), 512, 0, stream>>>(
        H, WT, b2, counts, offs, rowinfo, wslot, nullptr, out, IDIM, DDIM);
}

// Round 10
// 703.642 us; speedup vs baseline: 1.0676x; 1.0676x over previous
//
#include <hip/hip_runtime.h>
#include <hip/hip_bf16.h>
#include <stdint.h>

// Problem constants (B=2, L=2048 -> T=4096 tokens)
#define T_TOK 4096
#define DDIM  1024
#define IDIM  4096
#define NEXP  8
// padded row count for gathered matrices (worst-case 256-tile overhang)
#define GROWS (T_TOK*2 + 256)

typedef __attribute__((ext_vector_type(8))) short bfrag;   // 8 bf16 (4 VGPR)
typedef __attribute__((ext_vector_type(4))) float f32x4;   // MFMA accum

__device__ __forceinline__ unsigned short f2bf(float x) {
    unsigned int u = __float_as_uint(x);
    unsigned int r = u + 0x7FFFu + ((u >> 16) & 1u);   // RNE
    return (unsigned short)(r >> 16);
}
__device__ __forceinline__ float bf2f(unsigned short h) {
    return __uint_as_float(((unsigned int)h) << 16);
}

// async global->LDS, 16B per lane; LDS base must be wave-uniform
#define GLOAD16(gsrc, ldst)                                                     \
    __builtin_amdgcn_global_load_lds(                                           \
        (const __attribute__((address_space(1))) unsigned int*)(gsrc),          \
        (__attribute__((address_space(3))) unsigned int*)(ldst), 16, 0, 0)

// ---------------------------------------------------------------------------
// K1: per-token layernorm stats + xhat (bf16), fp32 router logits, top-2,
//     softmax -> per-slot weights; builds per-expert token lists via atomics.
// ---------------------------------------------------------------------------
__global__ __launch_bounds__(256) void router_kernel(
    const float* __restrict__ x,
    const float* __restrict__ rng, const float* __restrict__ rnb,
    const float* __restrict__ rw,  const float* __restrict__ rb,
    unsigned short* __restrict__ xhat,
    int* __restrict__ counts, int* __restrict__ tok_slot,
    float* __restrict__ wslot)
{
    const int t = blockIdx.x;
    const int tid = threadIdx.x;
    const int lane = tid & 63, wid = tid >> 6;

    float4 v = *(const float4*)(x + (size_t)t * DDIM + tid * 4);
    float s1 = v.x + v.y + v.z + v.w;
    float s2 = v.x*v.x + v.y*v.y + v.z*v.z + v.w*v.w;
    #pragma unroll
    for (int m = 32; m; m >>= 1) { s1 += __shfl_xor(s1, m, 64); s2 += __shfl_xor(s2, m, 64); }

    __shared__ float red[8];
    __shared__ float pl[4][8];
    __shared__ float bcast[2];
    if (lane == 0) { red[wid] = s1; red[wid + 4] = s2; }
    __syncthreads();
    if (tid == 0) {
        float S1 = red[0] + red[1] + red[2] + red[3];
        float S2 = red[4] + red[5] + red[6] + red[7];
        float mean = S1 * (1.f / 1024.f);
        float var  = S2 * (1.f / 1024.f) - mean * mean;
        bcast[0] = mean; bcast[1] = rsqrtf(var + 1e-5f);
    }
    __syncthreads();
    const float mean = bcast[0], rinv = bcast[1];

    float4 xh = { (v.x - mean) * rinv, (v.y - mean) * rinv,
                  (v.z - mean) * rinv, (v.w - mean) * rinv };
    ushort4 hx = { f2bf(xh.x), f2bf(xh.y), f2bf(xh.z), f2bf(xh.w) };
    *(ushort4*)(xhat + (size_t)t * DDIM + tid * 4) = hx;

    // router layernorm affine + logits (kept fp32 to match reference top-k)
    float4 g = *(const float4*)(rng + tid * 4);
    float4 b = *(const float4*)(rnb + tid * 4);
    float4 nm = { xh.x*g.x + b.x, xh.y*g.y + b.y, xh.z*g.z + b.z, xh.w*g.w + b.w };
    float p[8];
    #pragma unroll
    for (int e = 0; e < 8; e++) {
        float4 w = *(const float4*)(rw + e * DDIM + tid * 4);
        p[e] = nm.x*w.x + nm.y*w.y + nm.z*w.z + nm.w*w.w;
    }
    #pragma unroll
    for (int m = 32; m; m >>= 1) {
        #pragma unroll
        for (int e = 0; e < 8; e++) p[e] += __shfl_xor(p[e], m, 64);
    }
    if (lane == 0) {
        #pragma unroll
        for (int e = 0; e < 8; e++) pl[wid][e] = p[e];
    }
    __syncthreads();
    if (tid == 0) {
        float l[8];
        #pragma unroll
        for (int e = 0; e < 8; e++) l[e] = pl[0][e] + pl[1][e] + pl[2][e] + pl[3][e] + rb[e];
        int e0 = 0; float v0 = l[0];
        for (int e = 1; e < 8; e++) if (l[e] > v0) { v0 = l[e]; e0 = e; }
        int e1 = (e0 == 0) ? 1 : 0; float v1 = l[e1];
        for (int e = 0; e < 8; e++) if (e != e0 && l[e] > v1) { v1 = l[e]; e1 = e; }
        float ex = expf(v1 - v0);
        float w0 = 1.f / (1.f + ex);
        float w1 = ex * w0;
        int p0 = atomicAdd(&counts[e0], 1);
        tok_slot[e0 * T_TOK + p0] = (t << 1);
        int p1 = atomicAdd(&counts[e1], 1);
        tok_slot[e1 * T_TOK + p1] = (t << 1) | 1;
        wslot[t * 2]     = w0;
        wslot[t * 2 + 1] = w1;
    }
}

// K2: tiny exclusive prefix over 8 expert counts
__global__ void prefix_kernel(const int* __restrict__ counts, int* __restrict__ offs)
{
    if (threadIdx.x == 0) {
        int a = 0;
        for (int e = 0; e < 8; e++) { offs[e] = a; a += counts[e]; }
    }
}

// ---------------------------------------------------------------------------
// K3: build compacted per-expert A matrix: Agath[off[e]+pos][d] =
//     bf16( xhat[t][d]*ln_g[e][d] + ln_b[e][d] ), plus rowinfo for scatter.
// ---------------------------------------------------------------------------
__global__ __launch_bounds__(256) void gather_kernel(
    const unsigned short* __restrict__ xhat,
    const float* __restrict__ lng, const float* __restrict__ lnb,
    const int* __restrict__ counts, const int* __restrict__ offs,
    const int* __restrict__ tok_slot,
    unsigned short* __restrict__ Agath, int* __restrict__ rowinfo)
{
    const int e = blockIdx.y, pos = blockIdx.x;
    if (pos >= counts[e]) return;
    const int grow = offs[e] + pos;
    const int info = tok_slot[e * T_TOK + pos];
    if (threadIdx.x == 0) rowinfo[grow] = info;
    const int t = info >> 1;
    const int d = threadIdx.x * 4;
    ushort4 hx = *(const ushort4*)(xhat + (size_t)t * DDIM + d);
    float4 g = *(const float4*)(lng + (size_t)e * DDIM + d);
    float4 b = *(const float4*)(lnb + (size_t)e * DDIM + d);
    ushort4 o = { f2bf(bf2f(hx.x) * g.x + b.x),
                  f2bf(bf2f(hx.y) * g.y + b.y),
                  f2bf(bf2f(hx.z) * g.z + b.z),
                  f2bf(bf2f(hx.w) * g.w + b.w) };
    *(ushort4*)(Agath + (size_t)grow * DDIM + d) = o;
}

// ---------------------------------------------------------------------------
// K4: transpose+convert weights: W [E][Kd][Nd] fp32 -> WT [E][Nd][Kd] bf16.
// ---------------------------------------------------------------------------
__global__ __launch_bounds__(256) void transpose_kernel(
    const float* __restrict__ W, unsigned short* __restrict__ WT,
    int Kd, int Nd)
{
    const int e  = blockIdx.z;
    const int k0 = blockIdx.y * 64;
    const int n  = blockIdx.x * 256 + threadIdx.x;
    const float* src = W + (size_t)e * Kd * Nd + (size_t)k0 * Nd + n;
    unsigned short* dst = WT + ((size_t)e * Nd + n) * Kd + k0;
    unsigned short buf[64];
    #pragma unroll
    for (int j = 0; j < 64; j++)
        buf[j] = f2bf(src[(size_t)j * Nd]);
    #pragma unroll
    for (int c = 0; c < 8; c++)
        *(int4*)(dst + c * 8) = *(const int4*)(buf + c * 8);
}

// ---------------------------------------------------------------------------
// GEMM, occupancy-first variant:
//   BM=128 x BN=128, BK=64, 8 waves of 32x64 (wm=wid>>1 rows, wn=wid&1 cols),
//   acc[2][4] (32 VGPR) -> ~90 arch regs, __launch_bounds__(512,4) enforces
//   4 waves/SIMD. LDS = 2 slots x 32KB = 64KB -> 2 blocks/CU resident
//   (16 waves/CU) -- 2-4x the TLP of all prior rounds (the invariant-250us
//   hypothesis: latency chain exposed at 2 waves/SIMD).
//
// LDS layout = consume-order fragments (R9-proven: 0 bank conflicts):
//   slot s (s*32768): A [chunk c 0..15][lane][16B] then B at +16384.
//   chunk c <-> (frag i_glob=c>>1, kk=c&1); lane l holds row i_glob*16+(l&15),
//   k = kk*32+(l>>4)*8. Stage: wave wid loads chunks {2wid, 2wid+1} of A and B
//   (per-lane global addr carries the permutation; LDS dest linear).
//
// Pipeline: depth-1 prefetch, counted vmcnt(4) (never 0 mid-loop), raw
// barriers. Tile t: issue stage(t+1 -> other slot); vmcnt(4); barrier;
// ds_read+MFMA on slot t; lgkmcnt(0); barrier.
//
// Grid: 1-D, e=b&7 (XCD pin), r=b>>3, mt0=r&7, nt=r>>3; persistent-mt loop
// (mt = mt0+8k while mt*128<ne) -> zero dud blocks at balanced routing,
// correct up to ne=4096 worst case. mt inner -> B panel shared in XCD L2.
// EPI=0: +b1, exact GELU -> H (bf16). EPI=1: +b2, *combine-w, atomicAdd out.
// ---------------------------------------------------------------------------
template<int EPI>
__global__ __launch_bounds__(512, 4) void gemm_kernel(
    const unsigned short* __restrict__ Asrc,
    const unsigned short* __restrict__ Bsrc,
    const float* __restrict__ bias,
    const int* __restrict__ counts,
    const int* __restrict__ offs,
    const int* __restrict__ rowinfo,
    const float* __restrict__ wslot,
    unsigned short* __restrict__ Hout,
    float* __restrict__ Out,
    int Kd, int Nd)
{
    const int b   = blockIdx.x;
    const int e   = b & 7;
    const int r   = b >> 3;
    const int mt0 = r & 7;
    const int nt  = r >> 3;
    const int ne  = counts[e];
    const int n0  = nt * 128;

    const int tid  = threadIdx.x;     // 0..511
    const int lane = tid & 63;
    const int wid  = tid >> 6;        // 0..7
    const int wm   = wid >> 1;        // 0..3 (M)
    const int wn   = wid & 1;         // 0..1 (N)

    __shared__ unsigned short S[2 * 16384];   // 2 slots x 32KB
    char* const Sb = (char*)S;

    // wave-uniform LDS staging bases (chunks 2wid, 2wid+1)
    char* const aw = Sb + wid * 2048;
    char* const bw = Sb + 16384 + wid * 2048;
    // per-lane B source base (constant across mt)
    const unsigned short* const bbase =
        Bsrc + ((size_t)e * Nd + n0 + wid * 16 + (lane & 15)) * Kd + (lane >> 4) * 8;
    const int nt_k = Kd >> 6;
    const float* bg = bias + (size_t)e * Nd;

    for (int mt = mt0; mt * 128 < ne; mt += 8) {
        const int growbase = offs[e] + mt * 128;
        const unsigned short* ap =
            Asrc + (size_t)(growbase + wid * 16 + (lane & 15)) * Kd + (lane >> 4) * 8;
        const unsigned short* bp = bbase;

        f32x4 acc[2][4];
        #pragma unroll
        for (int i = 0; i < 2; i++)
            #pragma unroll
            for (int j = 0; j < 4; j++)
                acc[i][j] = (f32x4){0.f, 0.f, 0.f, 0.f};

        // ---- prologue: stage K-tile 0 into slot 0 ----
        GLOAD16(ap, aw);      GLOAD16(ap + 32, aw + 1024);
        GLOAD16(bp, bw);      GLOAD16(bp + 32, bw + 1024);
        ap += 64; bp += 64;

        for (int t = 0; t < nt_k; ++t) {
            const int s = (t & 1) * 32768;
            if (t + 1 < nt_k) {
                const int s2 = ((t + 1) & 1) * 32768;
                GLOAD16(ap, aw + s2);      GLOAD16(ap + 32, aw + s2 + 1024);
                GLOAD16(bp, bw + s2);      GLOAD16(bp + 32, bw + s2 + 1024);
                ap += 64; bp += 64;
                asm volatile("s_waitcnt vmcnt(4)" ::: "memory");  // stage(t) landed
            } else {
                asm volatile("s_waitcnt vmcnt(0)" ::: "memory");
            }
            __builtin_amdgcn_s_barrier();        // slot t resident for all waves

            const char* As_ = Sb + s;
            const char* Bs_ = Sb + s + 16384;
            #pragma unroll
            for (int kk = 0; kk < 2; kk++) {
                bfrag av[2], bv[4];
                #pragma unroll
                for (int i = 0; i < 2; i++)
                    av[i] = *(const bfrag*)(As_ + ((wm * 2 + i) * 2 + kk) * 1024 + lane * 16);
                #pragma unroll
                for (int j = 0; j < 4; j++)
                    bv[j] = *(const bfrag*)(Bs_ + ((wn * 4 + j) * 2 + kk) * 1024 + lane * 16);
                __builtin_amdgcn_s_setprio(1);
                #pragma unroll
                for (int i = 0; i < 2; i++)
                    #pragma unroll
                    for (int j = 0; j < 4; j++)
                        acc[i][j] = __builtin_amdgcn_mfma_f32_16x16x32_bf16(av[i], bv[j], acc[i][j], 0, 0, 0);
                __builtin_amdgcn_s_setprio(0);
            }
            asm volatile("s_waitcnt lgkmcnt(0)" ::: "memory");  // my slot-t reads done
            __builtin_amdgcn_s_barrier();        // all waves done -> slot may be overwritten
        }

        // ---- epilogue (C/D layout: col = lane&15, row = (lane>>4)*4 + reg) ----
        #pragma unroll
        for (int i = 0; i < 2; i++) {
            #pragma unroll
            for (int rr = 0; rr < 4; rr++) {
                int mrow = wm * 32 + i * 16 + ((lane >> 4) << 2) + rr;
                int pos = mt * 128 + mrow;
                if (pos >= ne) continue;
                if constexpr (EPI == 0) {
                    size_t rowoff = (size_t)(growbase + mrow) * Nd;
                    #pragma unroll
                    for (int j = 0; j < 4; j++) {
                        int col = n0 + wn * 64 + j * 16 + (lane & 15);
                        float y = acc[i][j][rr] + bg[col];
                        float gl = 0.5f * y * (1.f + erff(y * 0.70710678118654752f));
                        Hout[rowoff + col] = f2bf(gl);
                    }
                } else {
                    int info = rowinfo[growbase + mrow];
                    float wg = wslot[info];
                    float* op = Out + (size_t)(info >> 1) * Nd;
                    #pragma unroll
                    for (int j = 0; j < 4; j++) {
                        int col = n0 + wn * 64 + j * 16 + (lane & 15);
                        float y = acc[i][j][rr] + bg[col];
                        atomicAdd(op + col, wg * y);   // exactly 2 adds/elem -> deterministic
                    }
                }
            }
        }
    }
}

// ---------------------------------------------------------------------------
extern "C" void kernel_launch(void* const* d_in, const int* in_sizes, int n_in,
                              void* d_out, int out_size, void* d_ws, size_t ws_size,
                              hipStream_t stream)
{
    (void)in_sizes; (void)n_in;
    const float* hidden   = (const float*)d_in[0];
    const float* rn_g     = (const float*)d_in[1];
    const float* rn_b     = (const float*)d_in[2];
    const float* router_w = (const float*)d_in[3];
    const float* router_b = (const float*)d_in[4];
    const float* ln_g     = (const float*)d_in[5];
    const float* ln_b     = (const float*)d_in[6];
    const float* w1       = (const float*)d_in[7];
    const float* b1       = (const float*)d_in[8];
    const float* w2       = (const float*)d_in[9];
    const float* b2       = (const float*)d_in[10];
    float* out = (float*)d_out;

    // workspace layout (bytes), total ~162.2 MB
    //   xhat    @ 0           :  8,388,608  (4096 x 1024 bf16)
    //   Agath   @ 8,388,608   : 17,301,504  (8448 x 1024 bf16)
    //   H       @ 25,690,112  : 69,206,016  (8448 x 4096 bf16)
    //   WT      @ 94,896,128  : 67,108,864  (W1T, then reused for W2T)
    //   counts  @ 162,004,992 / offs / tok_slot / rowinfo / wslot
    char* ws = (char*)d_ws;
    unsigned short* xhat   = (unsigned short*)ws;
    unsigned short* Agath  = (unsigned short*)(ws + 8388608);
    unsigned short* H      = (unsigned short*)(ws + 25690112);
    unsigned short* WT     = (unsigned short*)(ws + 94896128);
    int*   counts   = (int*)(ws + 162004992);
    int*   offs     = (int*)(ws + 162005024);
    int*   tok_slot = (int*)(ws + 162005056);
    int*   rowinfo  = (int*)(ws + 162136128);
    float* wslot    = (float*)(ws + 162169920);
    if (ws_size < 162202688) return;   // fail loudly (validation will catch it)

    hipMemsetAsync(counts, 0, 64, stream);                 // counts + offs
    hipMemsetAsync(d_out, 0, (size_t)out_size * sizeof(float), stream);

    // W1 [8][1024][4096] -> W1T [8][4096][1024]
    transpose_kernel<<<dim3(IDIM / 256, DDIM / 64, NEXP), 256, 0, stream>>>(w1, WT, DDIM, IDIM);
    router_kernel<<<T_TOK, 256, 0, stream>>>(hidden, rn_g, rn_b, router_w, router_b,
                                             xhat, counts, tok_slot, wslot);
    prefix_kernel<<<1, 64, 0, stream>>>(counts, offs);
    gather_kernel<<<dim3(T_TOK, NEXP), 256, 0, stream>>>(xhat, ln_g, ln_b, counts, offs,
                                                         tok_slot, Agath, rowinfo);
    // GEMM1: [rows x 1024] x [1024 x 4096] + b1, GELU -> H
    //   grid = 8 e x 8 mt0 x 32 nt (persistent mt loop inside)
    gemm_kernel<0><<<dim3(8 * 8 * (IDIM / 128)), 512, 0, stream>>>(
        Agath, WT, b1, counts, offs, rowinfo, wslot, H, nullptr, DDIM, IDIM);
    // W2 [8][4096][1024] -> W2T [8][1024][4096] (reuses WT buffer after GEMM1)
    transpose_kernel<<<dim3(DDIM / 256, IDIM / 64, NEXP), 256, 0, stream>>>(w2, WT, IDIM, DDIM);
    // GEMM2: [rows x 4096] x [4096 x 1024] + b2, *w, scatter-add -> out
    //   grid = 8 e x 8 mt0 x 8 nt
    gemm_kernel<1><<<dim3(8 * 8 * (DDIM / 128)), 512, 0, stream>>>(
        H, WT, b2, counts, offs, rowinfo, wslot, nullptr, out, IDIM, DDIM);
}